// Round 7
// baseline (232.073 us; speedup 1.0000x reference)
//
#include <hip/hip_runtime.h>
#include <cstdint>
#include <cstddef>

// Causal self-attention, B=4 L=2048 D=1024 H=16 HD=64.
// I/O dtype: float32; internal compute bf16 MFMA.
// Round-17: (1) flash v9 — 128-col K-steps (two 64-col sub-steps per
// barrier): 34 -> 17 barriers/block, DMA batched 8 loads/step with a full
// 128-col compute window to land. Inner compute identical to v8 (S^T via
// mfma32(K,Q), in-reg P with cvt_pk+permlane32_swap). LDS 64KB, 2 blocks/CU.
// (2) prep kernels merged (f32->bf16 + both W transposes) -> 2 fewer
// launches. GEMMs unchanged from round-16 (128^2 TLP structure, 923 TF).

typedef __attribute__((ext_vector_type(8))) __bf16 bf16x8;
typedef __attribute__((ext_vector_type(4))) __bf16 bf16x4;
typedef __attribute__((ext_vector_type(4))) float f32x4;
typedef __attribute__((ext_vector_type(16))) float f32x16;

__device__ __forceinline__ f32x4 mfma_bf16(bf16x8 a, bf16x8 b, f32x4 c) {
  return __builtin_amdgcn_mfma_f32_16x16x32_bf16(a, b, c, 0, 0, 0);
}

__device__ __forceinline__ f32x16 mfma32(bf16x8 a, bf16x8 b, f32x16 c) {
  return __builtin_amdgcn_mfma_f32_32x32x16_bf16(a, b, c, 0, 0, 0);
}

__device__ __forceinline__ unsigned cvtpk(float a, float b) {
  unsigned r;
  asm("v_cvt_pk_bf16_f32 %0, %1, %2" : "=v"(r) : "v"(a), "v"(b));
  return r;
}

__device__ __forceinline__ void async_copy16(const void* gsrc, void* ldsdst) {
  __builtin_amdgcn_global_load_lds(
      (const __attribute__((address_space(1))) void*)gsrc,
      (__attribute__((address_space(3))) void*)ldsdst, 16, 0, 0);
}

// -------- merged prep: f32->bf16 (x) + W transposes (blocks partitioned) ----
__global__ __launch_bounds__(256) void prep(
    const float* __restrict__ x, __bf16* __restrict__ xb,
    const float* __restrict__ Wqkv, __bf16* __restrict__ WqkvT,
    const float* __restrict__ Wproj, __bf16* __restrict__ WprojT) {
  const int bid = blockIdx.x;
  if (bid < 8192) {
    const size_t i = ((size_t)bid * 256 + threadIdx.x) * 4;
    const float4 v = *(const float4*)&x[i];
    bf16x4 o = {(__bf16)v.x, (__bf16)v.y, (__bf16)v.z, (__bf16)v.w};
    *(bf16x4*)&xb[i] = o;
    return;
  }
  __shared__ float tile[32][33];
  const float* in;
  __bf16* out;
  int idx, gx, R, C;
  if (bid < 8192 + 3072) {
    idx = bid - 8192; in = Wqkv; out = WqkvT; R = 1024; C = 3072; gx = 96;
  } else {
    idx = bid - 11264; in = Wproj; out = WprojT; R = 1024; C = 1024; gx = 32;
  }
  const int c0 = (idx % gx) * 32;
  const int r0 = (idx / gx) * 32;
  const int tx = threadIdx.x & 31;
  const int ty = threadIdx.x >> 5;  // 0..7
#pragma unroll
  for (int i = 0; i < 32; i += 8)
    tile[ty + i][tx] = in[(size_t)(r0 + ty + i) * C + c0 + tx];
  __syncthreads();
#pragma unroll
  for (int i = 0; i < 32; i += 8)
    out[(size_t)(c0 + ty + i) * R + r0 + tx] = (__bf16)tile[tx][ty + i];
}

// ======== shared 128x128 GEMM core, BK=64, 4 waves (2Mx2N), 2-deep ==========
#define GEMM128x128_CORE(Aptr, Bptr)                                         \
  const int srow32 = tid >> 3; /* 0..31 */                                   \
  const int schunk = ((tid & 7) ^ (srow32 & 7)) << 3;                        \
  const __bf16* aBase = &(Aptr)[(size_t)(m0 + srow32) * 1024 + schunk];      \
  const __bf16* bBase = &(Bptr)[(size_t)(n0 + srow32) * 1024 + schunk];      \
  auto stgTile = [&](int kt, int b2) {                                       \
    __bf16* dst = smem + b2 * 16384 + wave * 512;                            \
    _Pragma("unroll") for (int u = 0; u < 4; ++u)                            \
        async_copy16(aBase + (size_t)u * 32768 + kt * 64, dst + u * 2048);   \
    _Pragma("unroll") for (int u = 0; u < 4; ++u)                            \
        async_copy16(bBase + (size_t)u * 32768 + kt * 64,                    \
                     dst + 8192 + u * 2048);                                 \
  };                                                                         \
  const f32x4 zero = {0.f, 0.f, 0.f, 0.f};                                   \
  f32x4 acc[4][4];                                                           \
  _Pragma("unroll") for (int i = 0; i < 4; ++i)                              \
      _Pragma("unroll") for (int j = 0; j < 4; ++j) acc[i][j] = zero;        \
  stgTile(0, 0);                                                             \
  asm volatile("s_waitcnt vmcnt(0)" ::: "memory");                           \
  __builtin_amdgcn_s_barrier();                                              \
  for (int t = 0; t < 16; ++t) {                                             \
    const __bf16* As = smem + (t & 1) * 16384;                               \
    const __bf16* Bs = As + 8192;                                            \
    bf16x8 af[4][2], bfr[4][2];                                              \
    _Pragma("unroll") for (int mt = 0; mt < 4; ++mt)                         \
        _Pragma("unroll") for (int kk = 0; kk < 2; ++kk) af[mt][kk] =        \
            *(const bf16x8*)&As[(wr * 64 + mt * 16 + n16) * 64 +             \
                                (((kk * 4 + quad) ^ (n16 & 7)) << 3)];       \
    _Pragma("unroll") for (int nt = 0; nt < 4; ++nt)                         \
        _Pragma("unroll") for (int kk = 0; kk < 2; ++kk) bfr[nt][kk] =       \
            *(const bf16x8*)&Bs[(wc * 64 + nt * 16 + n16) * 64 +             \
                                (((kk * 4 + quad) ^ (n16 & 7)) << 3)];       \
    if (t < 15) stgTile(t + 1, (t + 1) & 1);                                 \
    __builtin_amdgcn_s_barrier();                                            \
    asm volatile("s_waitcnt lgkmcnt(0)" ::: "memory");                       \
    __builtin_amdgcn_sched_barrier(0);                                       \
    __builtin_amdgcn_s_setprio(1);                                           \
    _Pragma("unroll") for (int mt = 0; mt < 4; ++mt)                         \
        _Pragma("unroll") for (int nt = 0; nt < 4; ++nt)                     \
            _Pragma("unroll") for (int kk = 0; kk < 2; ++kk)                 \
                acc[mt][nt] = mfma_bf16(af[mt][kk], bfr[nt][kk],             \
                                        acc[mt][nt]);                        \
    __builtin_amdgcn_s_setprio(0);                                           \
    asm volatile("s_waitcnt vmcnt(0)" ::: "memory");                         \
    __builtin_amdgcn_s_barrier();                                            \
  }

// ---------------- QKV GEMM: M=8192 N=3072, grid 1536 (3 exact rounds) -------
__global__ __launch_bounds__(256, 2) void gemm_qkv(
    const __bf16* __restrict__ A, const __bf16* __restrict__ BT,
    __bf16* __restrict__ Q, __bf16* __restrict__ Kh, __bf16* __restrict__ VT) {
  extern __shared__ __bf16 smem[];
  // bijective XCD swizzle: 1536 blocks, 192 per XCD
  const int wg = (blockIdx.x & 7) * 192 + (blockIdx.x >> 3);
  const int bm = wg / 24;  // 0..63
  const int bn = wg % 24;  // 0..23
  const int m0 = bm << 7;
  const int n0 = bn << 7;
  const int tid = threadIdx.x;
  const int wave = tid >> 6;
  const int lane = tid & 63;
  const int n16 = lane & 15;
  const int quad = lane >> 4;
  const int wr = wave >> 1;  // 0..1
  const int wc = wave & 1;   // 0..1

  GEMM128x128_CORE(A, BT)

  // ---- epilogue: 64x64 wave tile via 4KB/wave LDS scratch (round-1 code) ---
  __bf16* tw = smem + wave * 2048;
  const int b = m0 >> 11;  // 128 | 2048: block never straddles a batch
  const int l0w = (m0 & 2047) + wr * 64;
  const int n = n0 + wc * 64;  // 64-aligned -> exactly one head

  if (n < 2048) {
    const float QSCALE = 0.125f * 1.44269504089f;  // 1/sqrt(64)*log2(e)
    const bool isQ = (n < 1024);
    const int h = (n & 1023) >> 6;
    __bf16* dst = isQ ? Q : Kh;
    const size_t base = ((size_t)(b * 16 + h) * 2048) * 64;
#pragma unroll
    for (int pass = 0; pass < 2; ++pass) {
#pragma unroll
      for (int mt = 2 * pass; mt < 2 * pass + 2; ++mt) {
#pragma unroll
        for (int nt = 0; nt < 4; ++nt)
#pragma unroll
          for (int r = 0; r < 4; ++r) {
            const int hd = nt * 16 + n16;
            const int mm = (mt & 1) * 16 + quad * 4 + r;
            const float v = isQ ? acc[mt][nt][r] * QSCALE : acc[mt][nt][r];
            tw[mm * 64 + (((hd >> 3) ^ (mm & 7)) << 3) + (hd & 7)] =
                (__bf16)v;
          }
      }
#pragma unroll
      for (int i = 0; i < 4; ++i) {
        const int c = lane + 64 * i;
        const int row = c >> 3;  // l' within pass, 0..31
        const int hd0 = (c & 7) << 3;
        const int phys = (c & 7) ^ (row & 7);
        const bf16x8 v = *(const bf16x8*)&tw[row * 64 + phys * 8];
        *(bf16x8*)&dst[base + (size_t)(l0w + pass * 32 + row) * 64 + hd0] = v;
      }
    }
  } else {
    // V: transpose to VT[d][l], b128 stores along l.
    const int h = (n - 2048) >> 6;
    const size_t bhead = (size_t)(b * 16 + h);
#pragma unroll
    for (int pass = 0; pass < 2; ++pass) {
#pragma unroll
      for (int nt = 2 * pass; nt < 2 * pass + 2; ++nt) {
#pragma unroll
        for (int mt = 0; mt < 4; ++mt)
#pragma unroll
          for (int r = 0; r < 4; ++r) {
            const int hdp = (nt & 1) * 16 + n16;
            const int mm = mt * 16 + quad * 4 + r;
            const int phys = (mm >> 3) ^ (hdp & 7);
            tw[hdp * 64 + phys * 8 + (mm & 7)] = (__bf16)acc[mt][nt][r];
          }
      }
#pragma unroll
      for (int i = 0; i < 4; ++i) {
        const int c = lane + 64 * i;
        const int row = c >> 3;
        const int phys = (c & 7) ^ (row & 7);
        const bf16x8 v = *(const bf16x8*)&tw[row * 64 + phys * 8];
        *(bf16x8*)&VT[(bhead * 64 + pass * 32 + row) * 2048 + l0w +
                      (c & 7) * 8] = v;
      }
    }
  }
}

// ---------------- proj GEMM: M=8192 N=1024, grid 512 (1 exact round) --------
__global__ __launch_bounds__(256, 2) void gemm_bt_f32out(
    const __bf16* __restrict__ A, const __bf16* __restrict__ BT,
    float* __restrict__ C) {
  extern __shared__ __bf16 smem[];
  // bijective XCD swizzle: 512 blocks, 64 per XCD
  const int wg = (blockIdx.x & 7) * 64 + (blockIdx.x >> 3);
  const int bm = wg >> 3;  // 0..63
  const int bn = wg & 7;   // 0..7
  const int m0 = bm << 7;
  const int n0 = bn << 7;
  const int tid = threadIdx.x;
  const int wave = tid >> 6;
  const int lane = tid & 63;
  const int n16 = lane & 15;
  const int quad = lane >> 4;
  const int wr = wave >> 1;  // 0..1
  const int wc = wave & 1;   // 0..1

  GEMM128x128_CORE(A, BT)

  // direct f32 stores: 16-lane-contiguous n -> 64B segments
#pragma unroll
  for (int mt = 0; mt < 4; ++mt) {
#pragma unroll
    for (int r = 0; r < 4; ++r) {
      const int m = m0 + wr * 64 + mt * 16 + quad * 4 + r;
#pragma unroll
      for (int nt = 0; nt < 4; ++nt) {
        const int nn = n0 + wc * 64 + nt * 16 + n16;
        C[(size_t)m * 1024 + nn] = acc[mt][nt][r];
      }
    }
  }
}

// ---------------- flash attention v9 -----------------------------------------
// grid (64 bh, 8 p); block p does q-tiles p and 15-p (128 rows each; wave w
// owns rows w*32..+31). 128-col K-steps, two 64-col sub-steps per barrier:
// tile t needs t+1 steps -> 17 steps/block uniform, 17 barriers (was 34).
// Per step: {barrier (drains DMA) | stage next 128 cols (8 loads) | sub-step
// s=0,1: QK^T (mfma32(K,Q)) -> exp2 -> in-reg P (cvt_pk+permlane) -> PV}.
__global__ __launch_bounds__(256, 2) void flash_attn(
    const __bf16* __restrict__ Q, const __bf16* __restrict__ Kh,
    const __bf16* __restrict__ VT, __bf16* __restrict__ Y) {
  __shared__ __bf16 Ks[2][2][64 * 64];  // [buf][half][k-col][d], phys=c^(row&7)
  __shared__ __bf16 Vs[2][2][64 * 64];  // [buf][half][d][l], same swizzle
  const int bh = blockIdx.x;  // 0..63
  const int p = blockIdx.y;   // 0..7
  const int tid = threadIdx.x;
  const int wave = tid >> 6;
  const int lane = tid & 63;
  const int lrow = lane & 31;
  const int hi = lane >> 5;
  const int lswz = lane & 7;
  const __bf16* Qb = Q + (size_t)bh * 2048 * 64;
  const __bf16* Kb = Kh + (size_t)bh * 2048 * 64;
  const __bf16* Vb = VT + (size_t)bh * 64 * 2048;
  const int b = bh >> 4;
  const int h = bh & 15;
  const f32x16 zero16 = {0.f, 0.f, 0.f, 0.f, 0.f, 0.f, 0.f, 0.f,
                         0.f, 0.f, 0.f, 0.f, 0.f, 0.f, 0.f, 0.f};

  const int srow = tid >> 3;                       // 0..31
  const int sswz = ((tid & 7) ^ (srow & 7)) << 3;  // chunk pre-swizzle
  const int ldst = wave * 512;                     // wave-uniform unit base

  // stage 128 cols starting at cn into buf nb: 8 loads (K: half x rowblock,
  // V: rowblock x half). (row+32)&7 == row&7 so sswz valid for both rblocks.
  auto stageKV = [&](int cn, int nb) {
#pragma unroll
    for (int hf = 0; hf < 2; ++hf)
#pragma unroll
      for (int rb = 0; rb < 2; ++rb)
        async_copy16(&Kb[(size_t)(cn + hf * 64 + rb * 32 + srow) * 64 + sswz],
                     &Ks[nb][hf][rb * 2048 + ldst]);
#pragma unroll
    for (int hf = 0; hf < 2; ++hf)
#pragma unroll
      for (int rb = 0; rb < 2; ++rb)
        async_copy16(&Vb[(size_t)(rb * 32 + srow) * 2048 + cn + hf * 64 + sswz],
                     &Vs[nb][hf][rb * 2048 + ldst]);
  };

#pragma unroll
  for (int tt = 0; tt < 2; ++tt) {
    const int t = tt ? 15 - p : p;
    const int q0w = t * 128 + wave * 32;
    const int myq = q0w + lrow;

    bf16x8 qf[4];
#pragma unroll
    for (int i = 0; i < 4; ++i)
      qf[i] = *(const bf16x8*)&Qb[(size_t)myq * 64 + i * 16 + hi * 8];

    f32x16 o0 = zero16, o1 = zero16;
    float lsum = 0.f;
    const int nk = t + 1;  // 128-col steps

    __syncthreads();  // prior tile's readers of Ks/Vs done
    stageKV(0, 0);    // prologue DMA into buf0

    for (int kt = 0; kt < nk; ++kt) {
      const int buf = kt & 1;
      __syncthreads();  // drains DMA for buf; prior step's LDS reads done
      if (kt + 1 < nk) stageKV((kt + 1) << 7, buf ^ 1);

#pragma unroll
      for (int s = 0; s < 2; ++s) {
        const int c0s = (kt << 7) + (s << 6);
        if (c0s > q0w + 31) continue;  // fully masked sub-step for this wave
        const __bf16* ks = Ks[buf][s];
        const __bf16* vs = Vs[buf][s];

        // S^T chunks: sc[ch] covers k = c0s+ch*32+[(r&3)+8*(r>>2)+4*hi], q=lrow
        f32x16 sc[2];
#pragma unroll
        for (int ch = 0; ch < 2; ++ch) {
          sc[ch] = zero16;
#pragma unroll
          for (int i = 0; i < 4; ++i) {
            const bf16x8 kf = *(const bf16x8*)&ks[(ch * 32 + lrow) * 64 +
                                                  (((2 * i + hi) ^ lswz)
                                                   << 3)];
            sc[ch] = mfma32(kf, qf[i], sc[ch]);
          }
        }
        // exp2 (log2e folded into Q); mask only on the diagonal sub-step
        if (c0s + 63 > q0w) {
#pragma unroll
          for (int ch = 0; ch < 2; ++ch)
#pragma unroll
            for (int r = 0; r < 16; ++r) {
              const int k = c0s + ch * 32 + (r & 3) + 8 * (r >> 2) + 4 * hi;
              float e = __builtin_amdgcn_exp2f(sc[ch][r]);
              e = (k <= myq) ? e : 0.f;
              sc[ch][r] = e;
              lsum += e;
            }
        } else {
#pragma unroll
          for (int ch = 0; ch < 2; ++ch)
#pragma unroll
            for (int r = 0; r < 16; ++r) {
              const float e = __builtin_amdgcn_exp2f(sc[ch][r]);
              sc[ch][r] = e;
              lsum += e;
            }
        }
        // PV: per 16-k chunk build P A-frag in-register (T12), 2 d-tiles
#pragma unroll
        for (int ch = 0; ch < 2; ++ch) {
#pragma unroll
          for (int kc = 0; kc < 2; ++kc) {
            unsigned c01 = cvtpk(sc[ch][kc * 8 + 0], sc[ch][kc * 8 + 1]);
            unsigned c23 = cvtpk(sc[ch][kc * 8 + 2], sc[ch][kc * 8 + 3]);
            unsigned c45 = cvtpk(sc[ch][kc * 8 + 4], sc[ch][kc * 8 + 5]);
            unsigned c67 = cvtpk(sc[ch][kc * 8 + 6], sc[ch][kc * 8 + 7]);
            asm("v_permlane32_swap_b32 %0, %1" : "+v"(c01), "+v"(c45));
            asm("v_permlane32_swap_b32 %0, %1" : "+v"(c23), "+v"(c67));
            union {
              unsigned u[4];
              bf16x8 v;
            } pu;
            pu.u[0] = c01;  // P[q=lrow][k = hi*8 + 0,1]
            pu.u[1] = c23;
            pu.u[2] = c45;
            pu.u[3] = c67;
            const int kch = ch * 4 + kc * 2 + hi;
            {
              const bf16x8 vf0 = *(const bf16x8*)&vs[(0 * 32 + lrow) * 64 +
                                                     ((kch ^ lswz) << 3)];
              o0 = mfma32(pu.v, vf0, o0);
              const bf16x8 vf1 = *(const bf16x8*)&vs[(1 * 32 + lrow) * 64 +
                                                     ((kch ^ lswz) << 3)];
              o1 = mfma32(pu.v, vf1, o1);
            }
          }
        }
      }
    }

    // epilogue: lane's lsum covers q=lrow (its 32 of 64 k); partner lane^32
    // has the rest. O C-layout: col=d=lrow, row=q=(r&3)+8*(r>>2)+4*hi.
    lsum += __shfl_xor(lsum, 32);
    const float inv = 1.0f / lsum;
    float invr[16];
#pragma unroll
    for (int r = 0; r < 16; ++r)
      invr[r] = __shfl(inv, (r & 3) + 8 * (r >> 2) + 4 * hi);
#pragma unroll
    for (int r = 0; r < 16; ++r) {
      const int row = q0w + (r & 3) + 8 * (r >> 2) + 4 * hi;
      const size_t yb = (size_t)(b * 2048 + row) * 1024 + h * 64;
      Y[yb + lrow] = (__bf16)(o0[r] * invr[r]);
      Y[yb + 32 + lrow] = (__bf16)(o1[r] * invr[r]);
    }
  }
}

// ---------------- launch ------------------------------------------------------
extern "C" void kernel_launch(void* const* d_in, const int* in_sizes, int n_in,
                              void* d_out, int out_size, void* d_ws,
                              size_t ws_size, hipStream_t stream) {
  const float* x = (const float*)d_in[0];      // [4,2048,1024] f32
  const float* Wqkv = (const float*)d_in[1];   // [1024,3072] f32
  const float* Wproj = (const float*)d_in[2];  // [1024,1024] f32
  float* out = (float*)d_out;                  // [4,2048,1024] f32

  char* ws = (char*)d_ws;  // ~75 MB
  __bf16* xb = (__bf16*)ws;     ws += (size_t)8192 * 1024 * 2;
  __bf16* WqkvT = (__bf16*)ws;  ws += (size_t)3072 * 1024 * 2;
  __bf16* WprojT = (__bf16*)ws; ws += (size_t)1024 * 1024 * 2;
  __bf16* Qs = (__bf16*)ws;     ws += (size_t)64 * 2048 * 64 * 2;
  __bf16* Ks = (__bf16*)ws;     ws += (size_t)64 * 2048 * 64 * 2;
  __bf16* VTs = (__bf16*)ws;    ws += (size_t)64 * 64 * 2048 * 2;
  __bf16* attn = xb;  // xb is dead after gemm_qkv; reuse its space

  static bool attrSet = false;
  if (!attrSet) {
    hipFuncSetAttribute((const void*)gemm_qkv,
                        hipFuncAttributeMaxDynamicSharedMemorySize, 65536);
    hipFuncSetAttribute((const void*)gemm_bt_f32out,
                        hipFuncAttributeMaxDynamicSharedMemorySize, 65536);
    attrSet = true;
  }

  prep<<<12288, 256, 0, stream>>>(x, xb, Wqkv, WqkvT, Wproj, WprojT);
  gemm_qkv<<<1536, 256, 65536, stream>>>(xb, WqkvT, Qs, Ks, VTs);
  flash_attn<<<dim3(64, 8), 256, 0, stream>>>(Qs, Ks, VTs, attn);
  gemm_bt_f32out<<<512, 256, 65536, stream>>>(attn, WprojT, out);
}